// Round 22
// baseline (106.921 us; speedup 1.0000x reference)
//
#include <hip/hip_runtime.h>

// CONVERGED PORTFOLIO (r21, 106.04 us) + attn single-buffer K/V (4 blocks/CU A/B).
// Falsified alternatives (each mechanistically explained — do not retry):
//  - gemm1 8-phase 256x256 (r12/r14): barrier-structural stall at K=1024, 1 blk/CU.
//  - conv_h fused into gemm1 staging (r13): +6.3M bank conflicts, 57.5 us.
//  - m97 global_load_lds 2-phase (r3): -4 us vs reg-staged at K=1024.
//  - attn without LDS (r6): uncoalesced 12KB-stride lanes, 126 us.
//  - attn k-chunked LDS (r7): chunk stride bank-aligned, conflicts up 50%.
//  - attn 32x32 MFMA (r9-r11): f32x16 regs spill at w=4 cap; 1 blk/CU at w=2.
//  - attn interleaved qt map (r17): heavy blocks in dispatch tail -> +6.4 us.
// Wins: bf16 residual/LN (r21, -1.7), transpose_v fused into gemm1 (r20, -4.6),
//       prep fusion (r19, -4.3), attn XOR-swizzle (r16), split-j 8-wave attn (r8).

typedef unsigned short u16;
typedef unsigned int u32;
typedef __attribute__((ext_vector_type(8))) __bf16 bf16x8;
typedef __attribute__((ext_vector_type(4))) float f32x4;
typedef __attribute__((ext_vector_type(8))) unsigned short u16x8;
typedef __attribute__((ext_vector_type(4))) unsigned short u16x4;
typedef __attribute__((ext_vector_type(2))) unsigned int u32x2;
typedef __attribute__((ext_vector_type(4))) unsigned int u32x4;

#if defined(__has_builtin)
#if __has_builtin(__builtin_amdgcn_permlane32_swap) && __has_builtin(__builtin_amdgcn_permlane16_swap)
#define USE_PERMLANE 1
#endif
#endif
#ifndef USE_PERMLANE
#define USE_PERMLANE 0
#endif

__device__ __forceinline__ u16 f2bf(float f) {
    u32 u = __builtin_bit_cast(u32, f);
    u += 0x7fffu + ((u >> 16) & 1u);   // round-to-nearest-even
    return (u16)(u >> 16);
}

__device__ __forceinline__ float bf2f(u16 v) {
    return __builtin_bit_cast(float, (u32)v << 16);
}

__device__ __forceinline__ float fexp2(float x) {
#if __has_builtin(__builtin_amdgcn_exp2f)
    return __builtin_amdgcn_exp2f(x);
#else
    return exp2f(x);
#endif
}

__device__ __forceinline__ float frcp(float x) {
#if __has_builtin(__builtin_amdgcn_rcpf)
    return __builtin_amdgcn_rcpf(x);
#else
    return 1.0f / x;
#endif
}

// ---------------- fused prep: conv_h + Wqkv^T + Wo^T in ONE dispatch ----------------
__global__ __launch_bounds__(256) void prep_kernel(const float* __restrict__ h,
                                                   u16* __restrict__ hb,
                                                   const float* __restrict__ Wqkv,
                                                   u16* __restrict__ wqkvt,
                                                   const float* __restrict__ Wo,
                                                   u16* __restrict__ wot,
                                                   float qscale) {
    __shared__ float tile[32][33];
    const int bid = blockIdx.x;
    const int t = threadIdx.x;
    if (bid < 4096) {                     // conv_h
        int i = bid * 256 + t;
        float4 v = ((const float4*)h)[i];
        u16x4 o = { f2bf(v.x), f2bf(v.y), f2bf(v.z), f2bf(v.w) };
        ((u16x4*)hb)[i] = o;
        return;
    }
    const float* W;  u16* Wt;  int R, C, scale_rows;  float scale;  int bx, by;
    if (bid < 7168) {                     // Wqkv [1024][3072] -> [3072][1024]
        int idx = bid - 4096;
        bx = idx % 96;  by = idx / 96;
        W = Wqkv;  Wt = wqkvt;  R = 1024;  C = 3072;  scale_rows = 1024;  scale = qscale;
    } else {                              // Wo [1024][1024] -> [1024][1024]
        int idx = bid - 7168;
        bx = idx % 32;  by = idx / 32;
        W = Wo;  Wt = wot;  R = 1024;  C = 1024;  scale_rows = 0;  scale = 1.0f;
    }
    int r = t >> 3, c4 = (t & 7) * 4;
    int gx = bx * 32, gy = by * 32;
    float4 v = *(const float4*)&W[(size_t)(gy + r) * C + gx + c4];
    tile[r][c4 + 0] = v.x; tile[r][c4 + 1] = v.y;
    tile[r][c4 + 2] = v.z; tile[r][c4 + 3] = v.w;
    __syncthreads();
    float sc = (gx + r < scale_rows) ? scale : 1.0f;
    u16x4 o = { f2bf(tile[c4 + 0][r] * sc), f2bf(tile[c4 + 1][r] * sc),
                f2bf(tile[c4 + 2][r] * sc), f2bf(tile[c4 + 3][r] * sc) };
    *(u16x4*)&Wt[(size_t)(gx + r) * R + gy + c4] = o;
}

// ---------------- GEMM: C[M][N] = A[M][K] (bf16) x Bt[N][K]^T (bf16) ----------------
// reg-staged 2-phase, padded LDS. MODE 0 (gemm1): V-region blocks (n0>=2048) write
// TRANSPOSED into vt via LDS. MODE 1 (gemm2): bf16 residual (hb) + bf16 x out.
template <int MODE>
__global__ __launch_bounds__(256) void gemm_bt_kernel(
        const u16* __restrict__ A, const u16* __restrict__ Bt,
        u16* __restrict__ Cb, u16* __restrict__ vt,
        const u16* __restrict__ Hb, u16* __restrict__ Xb,
        int M, int N, int K) {
    constexpr int LDT = 40;                 // 32 + 8 pad (2-way bank alias = free)
    __shared__ u16 alds[2][128 * LDT];
    __shared__ u16 blds[2][128 * LDT];
    const int t = threadIdx.x;
    const int lane = t & 63;
    const int wave = t >> 6;
    const int wm = wave >> 1, wn = wave & 1;
    const int m0 = blockIdx.x * 128;
    const int n0 = blockIdx.y * 128;
    const int nk = K >> 5;

    const int srow = t >> 1;
    const int sch = (t & 1) * 2;
    const u16* ga = A + (size_t)(m0 + srow) * K + sch * 8;
    const u16* gb = Bt + (size_t)(n0 + srow) * K + sch * 8;
    const int wo = srow * LDT + sch * 8;

    u16x8 ra0 = *(const u16x8*)(ga);
    u16x8 ra1 = *(const u16x8*)(ga + 8);
    u16x8 rb0 = *(const u16x8*)(gb);
    u16x8 rb1 = *(const u16x8*)(gb + 8);
    *(u16x8*)&alds[0][wo] = ra0;  *(u16x8*)&alds[0][wo + 8] = ra1;
    *(u16x8*)&blds[0][wo] = rb0;  *(u16x8*)&blds[0][wo + 8] = rb1;

    f32x4 acc[4][4] = {};
    const int ko = (lane >> 4) * 8;
    const int arow_base = wm * 64 + (lane & 15);
    const int brow_base = wn * 64 + (lane & 15);

    int cur = 0;
    for (int kt = 0; kt < nk; ++kt) {
        __syncthreads();
        if (kt + 1 < nk) {
            const u16* gan = ga + (kt + 1) * 32;
            const u16* gbn = gb + (kt + 1) * 32;
            ra0 = *(const u16x8*)(gan);
            ra1 = *(const u16x8*)(gan + 8);
            rb0 = *(const u16x8*)(gbn);
            rb1 = *(const u16x8*)(gbn + 8);
        }
        bf16x8 afrag[4], bfrag[4];
#pragma unroll
        for (int m = 0; m < 4; ++m)
            afrag[m] = *(const bf16x8*)&alds[cur][(arow_base + m * 16) * LDT + ko];
#pragma unroll
        for (int n = 0; n < 4; ++n)
            bfrag[n] = *(const bf16x8*)&blds[cur][(brow_base + n * 16) * LDT + ko];
#pragma unroll
        for (int m = 0; m < 4; ++m)
#pragma unroll
            for (int n = 0; n < 4; ++n)
                acc[m][n] = __builtin_amdgcn_mfma_f32_16x16x32_bf16(afrag[m], bfrag[n],
                                                                   acc[m][n], 0, 0, 0);
        if (kt + 1 < nk) {
            *(u16x8*)&alds[cur ^ 1][wo] = ra0;  *(u16x8*)&alds[cur ^ 1][wo + 8] = ra1;
            *(u16x8*)&blds[cur ^ 1][wo] = rb0;  *(u16x8*)&blds[cur ^ 1][wo + 8] = rb1;
        }
        cur ^= 1;
    }

    if (MODE == 0 && n0 >= 2048) {
        // V-region: write transposed into vt[(p*64+dh)*2048 + seq], p = nn*2+b.
        u16* tl = &alds[0][0];              // reuse staging LDS
        const int seqb = m0 >> 1;
        const int pb = ((n0 - 2048) >> 6) * 2;
#pragma unroll
        for (int bb = 0; bb < 2; ++bb) {
            __syncthreads();
#pragma unroll
            for (int m = 0; m < 4; ++m)
#pragma unroll
                for (int r = 0; r < 4; ++r) {
                    int rl = wm * 64 + m * 16 + (lane >> 4) * 4 + r;
                    if ((rl & 1) == bb) {
                        int s = rl >> 1;
#pragma unroll
                        for (int n = 0; n < 4; ++n) {
                            int c = wn * 64 + n * 16 + (lane & 15);
                            tl[c * 72 + s] = f2bf(acc[m][n][r]);
                        }
                    }
                }
            __syncthreads();
            const int cb = t >> 3;
            const int sc = (t & 7) * 8;
#pragma unroll
            for (int it = 0; it < 4; ++it) {
                int c = cb + it * 32;
                int nnl = c >> 6, dh = c & 63;
                int p = pb + nnl * 2 + bb;
                u16* dst = vt + ((size_t)(p * 64 + dh)) * 2048 + seqb + sc;
                *(u16x8*)dst = *(const u16x8*)&tl[c * 72 + sc];
            }
        }
        return;
    }

#pragma unroll
    for (int m = 0; m < 4; ++m)
#pragma unroll
        for (int n = 0; n < 4; ++n)
#pragma unroll
            for (int r = 0; r < 4; ++r) {
                int row = m0 + wm * 64 + m * 16 + (lane >> 4) * 4 + r;
                int col = n0 + wn * 64 + n * 16 + (lane & 15);
                size_t idx = (size_t)row * N + col;
                if (MODE == 0) Cb[idx] = f2bf(acc[m][n][r]);
                else           Xb[idx] = f2bf(acc[m][n][r] + bf2f(Hb[idx]));
            }
}

// ---------------- causal flash attention (split-j, 8 waves, XOR-swz LDS) ----------
// Single-buffer K/V per group (32 KB total -> 4 blocks/CU, 4 independent streams);
// two barriers per tile-step (reads-done, writes-visible). T14 issue-early kept.
__global__ __launch_bounds__(512) void attn_kernel(const u16* __restrict__ qkvb,
                                                   const u16* __restrict__ vt,
                                                   u16* __restrict__ attnb) {
    __shared__ u16 kvs[2][2][4096];       // [group][K/V][row*64 + swz col] (32 KB)
#if !USE_PERMLANE
    __shared__ u16 plds[8][16 * 72];
#endif
    const int t = threadIdx.x;
    const int lane = t & 63;
    const int w = (t >> 6) & 3;           // wave within group
    const int grp = t >> 8;               // 0: even jt, 1: odd jt
    const int bid = blockIdx.x;
    const int qt = 31 - (bid >> 5);       // heavy q-tiles dispatched first (LPT)
    const int p = bid & 31;
    const int nn = p >> 1, b = p & 1;
    const int i0 = qt * 64;

    const int li = lane & 15;
    const int lg = lane >> 4;

    const int qrow = i0 + w * 16 + li;
    const u16* qg = qkvb + ((size_t)qrow * 2 + b) * 3072 + nn * 64 + lg * 8;
    bf16x8 qa0 = *(const bf16x8*)(qg);
    bf16x8 qa1 = *(const bf16x8*)(qg + 32);

    f32x4 o[4] = {};                      // O[row = lg*4+r][d = cf*16+li]
    float mrun = -3.0e38f;
    float lrun = 0.f;

    const int tg = t & 255;
    const int srow = tg >> 2;             // 0..63
    const int sch = (tg & 3) * 2;         // slots {sch, sch+1}
    const u16* kg = qkvb + 1024 + nn * 64 + sch * 8;
    const u16* vg = vt + ((size_t)p * 64 + srow) * 2048 + sch * 8;
    const int swo0 = srow * 64 + ((sch ^ (srow & 7)) << 3);
    const int swo1 = srow * 64 + (((sch + 1) ^ (srow & 7)) << 3);

    const int rsk0 = (lg ^ (li & 7)) << 3;          // QK^T cols [lg*8 .. )
    const int rsk1 = ((4 + lg) ^ (li & 7)) << 3;    // QK^T cols [32+lg*8 .. )

    const int nt = qt + 1;
    const int G = (nt + 1) >> 1;          // rounds per group

    u16x8 k0, k1, v0, v1;
    if (grp < nt) {                       // stage my first tile (jt = grp)
        const u16* kgp = kg + ((size_t)(grp * 64 + srow) * 2 + b) * 3072;
        k0 = *(const u16x8*)(kgp);  k1 = *(const u16x8*)(kgp + 8);
        const u16* vgp = vg + grp * 64;
        v0 = *(const u16x8*)(vgp);  v1 = *(const u16x8*)(vgp + 8);
        *(u16x8*)&kvs[grp][0][swo0] = k0;  *(u16x8*)&kvs[grp][0][swo1] = k1;
        *(u16x8*)&kvs[grp][1][swo0] = v0;  *(u16x8*)&kvs[grp][1][swo1] = v1;
    }
    __syncthreads();

    for (int s = 0; s < G; ++s) {
        const int jt = 2 * s + grp;
        const bool active = jt < nt;      // only group 1's last round can be inactive
        if (jt + 2 < nt) {                // issue-early my next tile (T14)
            const u16* kgp = kg + ((size_t)((jt + 2) * 64 + srow) * 2 + b) * 3072;
            k0 = *(const u16x8*)(kgp);  k1 = *(const u16x8*)(kgp + 8);
            const u16* vgp = vg + (jt + 2) * 64;
            v0 = *(const u16x8*)(vgp);  v1 = *(const u16x8*)(vgp + 8);
        }

        if (active) {
            const u16* kl = &kvs[grp][0][0];
            const u16* vl = &kvs[grp][1][0];

            // swapped QK^T: st[cf][r] = S^T[j = jt*64+cf*16+lg*4+r][i = i0+w*16+li]
            f32x4 st[4];
            __builtin_amdgcn_s_setprio(1);
#pragma unroll
            for (int cf = 0; cf < 4; ++cf) {
                bf16x8 kb0 = *(const bf16x8*)&kl[(cf * 16 + li) * 64 + rsk0];
                bf16x8 kb1 = *(const bf16x8*)&kl[(cf * 16 + li) * 64 + rsk1];
                f32x4 z = {};
                z = __builtin_amdgcn_mfma_f32_16x16x32_bf16(kb0, qa0, z, 0, 0, 0);
                z = __builtin_amdgcn_mfma_f32_16x16x32_bf16(kb1, qa1, z, 0, 0, 0);
                st[cf] = z;
            }
            __builtin_amdgcn_s_setprio(0);

            if (jt == qt) {               // mask only the diagonal tile
                const int it = w * 16 + li;
#pragma unroll
                for (int cf = 0; cf < 4; ++cf)
#pragma unroll
                    for (int r = 0; r < 4; ++r) {
                        int jl = cf * 16 + lg * 4 + r;
                        if (jl > it) st[cf][r] = -3.0e38f;
                    }
            }

            // row max: 15 in-reg + 2 shuffles
            float mloc = st[0][0];
#pragma unroll
            for (int cf = 0; cf < 4; ++cf)
#pragma unroll
                for (int r = 0; r < 4; ++r) mloc = fmaxf(mloc, st[cf][r]);
            mloc = fmaxf(mloc, __shfl_xor(mloc, 16, 64));
            mloc = fmaxf(mloc, __shfl_xor(mloc, 32, 64));

            // defer-rescale (T13)
            if (__any(mloc > mrun + 8.0f)) {
                float mnew = fmaxf(mrun, mloc);
                float alpha = fexp2(mrun - mnew);
                lrun *= alpha;
                mrun = mnew;
#pragma unroll
                for (int r = 0; r < 4; ++r) {
                    float ar = __shfl(alpha, lg * 4 + r, 64);
#pragma unroll
                    for (int cf = 0; cf < 4; ++cf) o[cf][r] *= ar;
                }
            }

#if USE_PERMLANE
            float rsum = 0.f;
            u32 wv[4][2];
#pragma unroll
            for (int cf = 0; cf < 4; ++cf)
#pragma unroll
                for (int rr = 0; rr < 2; ++rr) {
                    float p0 = fexp2(st[cf][2 * rr] - mrun);
                    float p1 = fexp2(st[cf][2 * rr + 1] - mrun);
                    rsum += p0 + p1;
                    u32 wres;
                    asm("v_cvt_pk_bf16_f32 %0, %1, %2" : "=v"(wres) : "v"(p0), "v"(p1));
                    wv[cf][rr] = wres;
                }
            rsum += __shfl_xor(rsum, 16, 64);
            rsum += __shfl_xor(rsum, 32, 64);
            lrun += rsum;

            __builtin_amdgcn_s_setprio(1);
#pragma unroll
            for (int ks = 0; ks < 2; ++ks) {
                u32x2 sa = __builtin_amdgcn_permlane32_swap(wv[2 * ks][0], wv[2 * ks + 1][0], false, false);
                u32x2 fa = __builtin_amdgcn_permlane16_swap(sa[0], sa[1], false, false);
                u32x2 sb = __builtin_amdgcn_permlane32_swap(wv[2 * ks][1], wv[2 * ks + 1][1], false, false);
                u32x2 fb = __builtin_amdgcn_permlane16_swap(sb[0], sb[1], false, false);
                u32x4 fw = { fa[0], fb[0], fa[1], fb[1] };
                bf16x8 pa = __builtin_bit_cast(bf16x8, fw);
#pragma unroll
                for (int cf = 0; cf < 4; ++cf) {
                    bf16x8 vb = *(const bf16x8*)&vl[(cf * 16 + li) * 64
                                                    + (((ks * 4 + lg) ^ (li & 7)) << 3)];
                    o[cf] = __builtin_amdgcn_mfma_f32_16x16x32_bf16(pa, vb, o[cf], 0, 0, 0);
                }
            }
            __builtin_amdgcn_s_setprio(0);
#else
            float rsum = 0.f;
#pragma unroll
            for (int cf = 0; cf < 4; ++cf) {
                u16x4 pw;
#pragma unroll
                for (int r = 0; r < 4; ++r) {
                    float pv = fexp2(st[cf][r] - mrun);
                    rsum += pv;
                    pw[r] = f2bf(pv);
                }
                *(u16x4*)&plds[t >> 6][li * 72 + cf * 16 + lg * 4] = pw;
            }
            rsum += __shfl_xor(rsum, 16, 64);
            rsum += __shfl_xor(rsum, 32, 64);
            lrun += rsum;

            asm volatile("s_waitcnt lgkmcnt(0)" ::: "memory");
            __builtin_amdgcn_sched_barrier(0);

#pragma unroll
            for (int ks = 0; ks < 2; ++ks) {
                bf16x8 pa = *(const bf16x8*)&plds[t >> 6][li * 72 + ks * 32 + lg * 8];
#pragma unroll
                for (int cf = 0; cf < 4; ++cf) {
                    bf16x8 vb = *(const bf16x8*)&vl[(cf * 16 + li) * 64
                                                    + (((ks * 4 + lg) ^ (li & 7)) << 3)];
                    o[cf] = __builtin_amdgcn_mfma_f32_16x16x32_bf16(pa, vb, o[cf], 0, 0, 0);
                }
            }
#endif
        }

        __syncthreads();                  // all reads of kvs done (both groups)
        if (jt + 2 < nt) {                // overwrite my buffer with tile jt+2
            *(u16x8*)&kvs[grp][0][swo0] = k0;  *(u16x8*)&kvs[grp][0][swo1] = k1;
            *(u16x8*)&kvs[grp][1][swo0] = v0;  *(u16x8*)&kvs[grp][1][swo1] = v1;
        }
        __syncthreads();                  // writes visible
    }

    // ---- merge group partials (online-softmax combine) ----
    float* osc = (float*)&kvs[0][0][0];          // [64 rows][65] f32 (17.2 KB <= 32 KB)
    float* msc = osc + 64 * 65;                  // [64]
    float* lsc = msc + 64;                       // [64]
    if (grp == 1) {
#pragma unroll
        for (int cf = 0; cf < 4; ++cf)
#pragma unroll
            for (int r = 0; r < 4; ++r)
                osc[(w * 16 + lg * 4 + r) * 65 + cf * 16 + li] = o[cf][r];
        if (lg == 0) { msc[w * 16 + li] = mrun; lsc[w * 16 + li] = lrun; }
    }
    __syncthreads();
    if (grp == 0) {
        float mB = msc[w * 16 + li];
        float lB = lsc[w * 16 + li];
        float m = fmaxf(mrun, mB);
        float eA = fexp2(mrun - m);
        float eB = fexp2(mB - m);
        float linv = frcp(lrun * eA + lB * eB);
#pragma unroll
        for (int r = 0; r < 4; ++r) {
            float eAr = __shfl(eA, lg * 4 + r, 64);
            float eBr = __shfl(eB, lg * 4 + r, 64);
            float rvr = __shfl(linv, lg * 4 + r, 64);
            int row = i0 + w * 16 + lg * 4 + r;
            u16* og = attnb + ((size_t)row * 2 + b) * 1024 + nn * 64;
#pragma unroll
            for (int cf = 0; cf < 4; ++cf) {
                float ob = osc[(w * 16 + lg * 4 + r) * 65 + cf * 16 + li];
                og[cf * 16 + li] = f2bf((o[cf][r] * eAr + ob * eBr) * rvr);
            }
        }
    }
}

// ---------------- residual LayerNorm (bf16 x input, f32 stats, f32 out) ----------
__global__ __launch_bounds__(256) void ln_kernel(const u16* __restrict__ Xb,
                                                 const float* __restrict__ gamma,
                                                 const float* __restrict__ beta,
                                                 float* __restrict__ out) {
    __shared__ float red[8];
    const int t = threadIdx.x;
    const int row = blockIdx.x;
    u16x4 raw = ((const u16x4*)(Xb + (size_t)row * 1024))[t];
    float vx = bf2f(raw[0]), vy = bf2f(raw[1]), vz = bf2f(raw[2]), vw = bf2f(raw[3]);
    float s = vx + vy + vz + vw;
#pragma unroll
    for (int off = 1; off < 64; off <<= 1) s += __shfl_xor(s, off, 64);
    if ((t & 63) == 0) red[t >> 6] = s;
    __syncthreads();
    float mu = (red[0] + red[1] + red[2] + red[3]) * (1.f / 1024.f);
    float dx = vx - mu, dy = vy - mu, dz = vz - mu, dw = vw - mu;
    float q = dx * dx + dy * dy + dz * dz + dw * dw;
#pragma unroll
    for (int off = 1; off < 64; off <<= 1) q += __shfl_xor(q, off, 64);
    if ((t & 63) == 0) red[4 + (t >> 6)] = q;
    __syncthreads();
    float var = (red[4] + red[5] + red[6] + red[7]) * (1.f / 1024.f);
    float rs = rsqrtf(var + 1e-5f);
    float4 g = ((const float4*)gamma)[t];
    float4 bt = ((const float4*)beta)[t];
    float4 o;
    o.x = dx * rs * g.x + bt.x;
    o.y = dy * rs * g.y + bt.y;
    o.z = dz * rs * g.z + bt.z;
    o.w = dw * rs * g.w + bt.w;
    ((float4*)(out + (size_t)row * 1024))[t] = o;
}

// ---------------- launch ----------------
extern "C" void kernel_launch(void* const* d_in, const int* in_sizes, int n_in,
                              void* d_out, int out_size, void* d_ws, size_t ws_size,
                              hipStream_t stream) {
    const float* h     = (const float*)d_in[0];
    // d_in[1] = attn_mask (deterministic causal triu; applied analytically)
    const float* Wqkv  = (const float*)d_in[2];
    const float* Wo    = (const float*)d_in[3];
    const float* gamma = (const float*)d_in[4];
    const float* beta  = (const float*)d_in[5];
    float* out = (float*)d_out;

    char* ws = (char*)d_ws;
    u16*   hb    = (u16*)(ws);
    u16*   wqkvt = (u16*)(ws + 8388608);
    u16*   wot   = (u16*)(ws + 14680064);
    u16*   qkvb  = (u16*)(ws + 16777216);
    u16*   vt    = (u16*)(ws + 41943040);
    u16*   attnb = (u16*)(ws + 50331648);
    u16*   xb    = (u16*)(ws + 58720256);    // bf16 x = h + attn_out (8.4 MB)

    const float qscale = 0.125f * 1.44269504088896f;  // 1/sqrt(Dh) * log2(e)

    prep_kernel<<<8192, 256, 0, stream>>>(h, hb, Wqkv, wqkvt, Wo, wot, qscale);
    gemm_bt_kernel<0><<<dim3(32, 24), 256, 0, stream>>>(hb, wqkvt, qkvb, vt,
                                                        nullptr, nullptr, 4096, 3072, 1024);
    attn_kernel<<<1024, 512, 0, stream>>>(qkvb, vt, attnb);
    gemm_bt_kernel<1><<<dim3(32, 8), 256, 0, stream>>>(attnb, wot, nullptr, nullptr,
                                                       hb, xb, 4096, 1024, 1024);
    ln_kernel<<<4096, 256, 0, stream>>>(xb, gamma, beta, out);
}

// Round 23
// 105.902 us; speedup vs baseline: 1.0096x; 1.0096x over previous
//
#include <hip/hip_runtime.h>

// FINAL BUILD (r21 config, session-best 106.04 us; r22 single-buffer A/B falsified:
// +0.9 us, occupancy gain absorbed by extra barrier). Trajectory 197 -> 106 us.
// Falsified alternatives (each mechanistically explained — do not retry):
//  - gemm1 8-phase 256x256 (r12/r14): barrier-structural stall at K=1024, 1 blk/CU.
//  - conv_h fused into gemm1 staging (r13): +6.3M bank conflicts, 57.5 us.
//  - m97 global_load_lds 2-phase (r3): -4 us vs reg-staged at K=1024.
//  - attn without LDS (r6): uncoalesced 12KB-stride lanes, 126 us.
//  - attn k-chunked LDS (r7): chunk stride bank-aligned, conflicts up 50%.
//  - attn 32x32 MFMA (r9-r11): f32x16 regs spill at w=4 cap; 1 blk/CU at w=2.
//  - attn interleaved qt map (r17): heavy blocks in dispatch tail -> +6.4 us.
//  - attn single-buffer K/V (r22): 2x barriers ate the 4-stream occupancy gain.
// Wins: bf16 residual/LN (r21, -1.7), transpose_v fused into gemm1 (r20, -4.6),
//       prep fusion (r19, -4.3), attn XOR-swizzle (r16, -1.2, conflicts /17.5),
//       split-j 8-wave attn (r8), permlane P-exchange (r4), swapped-QK^T exp2 (r2).

typedef unsigned short u16;
typedef unsigned int u32;
typedef __attribute__((ext_vector_type(8))) __bf16 bf16x8;
typedef __attribute__((ext_vector_type(4))) float f32x4;
typedef __attribute__((ext_vector_type(8))) unsigned short u16x8;
typedef __attribute__((ext_vector_type(4))) unsigned short u16x4;
typedef __attribute__((ext_vector_type(2))) unsigned int u32x2;
typedef __attribute__((ext_vector_type(4))) unsigned int u32x4;

#if defined(__has_builtin)
#if __has_builtin(__builtin_amdgcn_permlane32_swap) && __has_builtin(__builtin_amdgcn_permlane16_swap)
#define USE_PERMLANE 1
#endif
#endif
#ifndef USE_PERMLANE
#define USE_PERMLANE 0
#endif

__device__ __forceinline__ u16 f2bf(float f) {
    u32 u = __builtin_bit_cast(u32, f);
    u += 0x7fffu + ((u >> 16) & 1u);   // round-to-nearest-even
    return (u16)(u >> 16);
}

__device__ __forceinline__ float bf2f(u16 v) {
    return __builtin_bit_cast(float, (u32)v << 16);
}

__device__ __forceinline__ float fexp2(float x) {
#if __has_builtin(__builtin_amdgcn_exp2f)
    return __builtin_amdgcn_exp2f(x);
#else
    return exp2f(x);
#endif
}

__device__ __forceinline__ float frcp(float x) {
#if __has_builtin(__builtin_amdgcn_rcpf)
    return __builtin_amdgcn_rcpf(x);
#else
    return 1.0f / x;
#endif
}

// ---------------- fused prep: conv_h + Wqkv^T + Wo^T in ONE dispatch ----------------
__global__ __launch_bounds__(256) void prep_kernel(const float* __restrict__ h,
                                                   u16* __restrict__ hb,
                                                   const float* __restrict__ Wqkv,
                                                   u16* __restrict__ wqkvt,
                                                   const float* __restrict__ Wo,
                                                   u16* __restrict__ wot,
                                                   float qscale) {
    __shared__ float tile[32][33];
    const int bid = blockIdx.x;
    const int t = threadIdx.x;
    if (bid < 4096) {                     // conv_h
        int i = bid * 256 + t;
        float4 v = ((const float4*)h)[i];
        u16x4 o = { f2bf(v.x), f2bf(v.y), f2bf(v.z), f2bf(v.w) };
        ((u16x4*)hb)[i] = o;
        return;
    }
    const float* W;  u16* Wt;  int R, C, scale_rows;  float scale;  int bx, by;
    if (bid < 7168) {                     // Wqkv [1024][3072] -> [3072][1024]
        int idx = bid - 4096;
        bx = idx % 96;  by = idx / 96;
        W = Wqkv;  Wt = wqkvt;  R = 1024;  C = 3072;  scale_rows = 1024;  scale = qscale;
    } else {                              // Wo [1024][1024] -> [1024][1024]
        int idx = bid - 7168;
        bx = idx % 32;  by = idx / 32;
        W = Wo;  Wt = wot;  R = 1024;  C = 1024;  scale_rows = 0;  scale = 1.0f;
    }
    int r = t >> 3, c4 = (t & 7) * 4;
    int gx = bx * 32, gy = by * 32;
    float4 v = *(const float4*)&W[(size_t)(gy + r) * C + gx + c4];
    tile[r][c4 + 0] = v.x; tile[r][c4 + 1] = v.y;
    tile[r][c4 + 2] = v.z; tile[r][c4 + 3] = v.w;
    __syncthreads();
    float sc = (gx + r < scale_rows) ? scale : 1.0f;
    u16x4 o = { f2bf(tile[c4 + 0][r] * sc), f2bf(tile[c4 + 1][r] * sc),
                f2bf(tile[c4 + 2][r] * sc), f2bf(tile[c4 + 3][r] * sc) };
    *(u16x4*)&Wt[(size_t)(gx + r) * R + gy + c4] = o;
}

// ---------------- GEMM: C[M][N] = A[M][K] (bf16) x Bt[N][K]^T (bf16) ----------------
// reg-staged 2-phase, padded LDS. MODE 0 (gemm1): V-region blocks (n0>=2048) write
// TRANSPOSED into vt via LDS. MODE 1 (gemm2): bf16 residual (hb) + bf16 x out.
template <int MODE>
__global__ __launch_bounds__(256) void gemm_bt_kernel(
        const u16* __restrict__ A, const u16* __restrict__ Bt,
        u16* __restrict__ Cb, u16* __restrict__ vt,
        const u16* __restrict__ Hb, u16* __restrict__ Xb,
        int M, int N, int K) {
    constexpr int LDT = 40;                 // 32 + 8 pad (2-way bank alias = free)
    __shared__ u16 alds[2][128 * LDT];
    __shared__ u16 blds[2][128 * LDT];
    const int t = threadIdx.x;
    const int lane = t & 63;
    const int wave = t >> 6;
    const int wm = wave >> 1, wn = wave & 1;
    const int m0 = blockIdx.x * 128;
    const int n0 = blockIdx.y * 128;
    const int nk = K >> 5;

    const int srow = t >> 1;
    const int sch = (t & 1) * 2;
    const u16* ga = A + (size_t)(m0 + srow) * K + sch * 8;
    const u16* gb = Bt + (size_t)(n0 + srow) * K + sch * 8;
    const int wo = srow * LDT + sch * 8;

    u16x8 ra0 = *(const u16x8*)(ga);
    u16x8 ra1 = *(const u16x8*)(ga + 8);
    u16x8 rb0 = *(const u16x8*)(gb);
    u16x8 rb1 = *(const u16x8*)(gb + 8);
    *(u16x8*)&alds[0][wo] = ra0;  *(u16x8*)&alds[0][wo + 8] = ra1;
    *(u16x8*)&blds[0][wo] = rb0;  *(u16x8*)&blds[0][wo + 8] = rb1;

    f32x4 acc[4][4] = {};
    const int ko = (lane >> 4) * 8;
    const int arow_base = wm * 64 + (lane & 15);
    const int brow_base = wn * 64 + (lane & 15);

    int cur = 0;
    for (int kt = 0; kt < nk; ++kt) {
        __syncthreads();
        if (kt + 1 < nk) {
            const u16* gan = ga + (kt + 1) * 32;
            const u16* gbn = gb + (kt + 1) * 32;
            ra0 = *(const u16x8*)(gan);
            ra1 = *(const u16x8*)(gan + 8);
            rb0 = *(const u16x8*)(gbn);
            rb1 = *(const u16x8*)(gbn + 8);
        }
        bf16x8 afrag[4], bfrag[4];
#pragma unroll
        for (int m = 0; m < 4; ++m)
            afrag[m] = *(const bf16x8*)&alds[cur][(arow_base + m * 16) * LDT + ko];
#pragma unroll
        for (int n = 0; n < 4; ++n)
            bfrag[n] = *(const bf16x8*)&blds[cur][(brow_base + n * 16) * LDT + ko];
#pragma unroll
        for (int m = 0; m < 4; ++m)
#pragma unroll
            for (int n = 0; n < 4; ++n)
                acc[m][n] = __builtin_amdgcn_mfma_f32_16x16x32_bf16(afrag[m], bfrag[n],
                                                                   acc[m][n], 0, 0, 0);
        if (kt + 1 < nk) {
            *(u16x8*)&alds[cur ^ 1][wo] = ra0;  *(u16x8*)&alds[cur ^ 1][wo + 8] = ra1;
            *(u16x8*)&blds[cur ^ 1][wo] = rb0;  *(u16x8*)&blds[cur ^ 1][wo + 8] = rb1;
        }
        cur ^= 1;
    }

    if (MODE == 0 && n0 >= 2048) {
        // V-region: write transposed into vt[(p*64+dh)*2048 + seq], p = nn*2+b.
        u16* tl = &alds[0][0];              // reuse staging LDS
        const int seqb = m0 >> 1;
        const int pb = ((n0 - 2048) >> 6) * 2;
#pragma unroll
        for (int bb = 0; bb < 2; ++bb) {
            __syncthreads();
#pragma unroll
            for (int m = 0; m < 4; ++m)
#pragma unroll
                for (int r = 0; r < 4; ++r) {
                    int rl = wm * 64 + m * 16 + (lane >> 4) * 4 + r;
                    if ((rl & 1) == bb) {
                        int s = rl >> 1;
#pragma unroll
                        for (int n = 0; n < 4; ++n) {
                            int c = wn * 64 + n * 16 + (lane & 15);
                            tl[c * 72 + s] = f2bf(acc[m][n][r]);
                        }
                    }
                }
            __syncthreads();
            const int cb = t >> 3;
            const int sc = (t & 7) * 8;
#pragma unroll
            for (int it = 0; it < 4; ++it) {
                int c = cb + it * 32;
                int nnl = c >> 6, dh = c & 63;
                int p = pb + nnl * 2 + bb;
                u16* dst = vt + ((size_t)(p * 64 + dh)) * 2048 + seqb + sc;
                *(u16x8*)dst = *(const u16x8*)&tl[c * 72 + sc];
            }
        }
        return;
    }

#pragma unroll
    for (int m = 0; m < 4; ++m)
#pragma unroll
        for (int n = 0; n < 4; ++n)
#pragma unroll
            for (int r = 0; r < 4; ++r) {
                int row = m0 + wm * 64 + m * 16 + (lane >> 4) * 4 + r;
                int col = n0 + wn * 64 + n * 16 + (lane & 15);
                size_t idx = (size_t)row * N + col;
                if (MODE == 0) Cb[idx] = f2bf(acc[m][n][r]);
                else           Xb[idx] = f2bf(acc[m][n][r] + bf2f(Hb[idx]));
            }
}

// ---------------- causal flash attention (split-j, 8 waves, XOR-swz LDS) ----------
// r8 structure, heavy-first qt (LPT-optimal), [64][64] LDS with 16B-slot XOR
// swizzle on writes and reads, double-buffered K/V, permlane P-exchange.
__global__ __launch_bounds__(512) void attn_kernel(const u16* __restrict__ qkvb,
                                                   const u16* __restrict__ vt,
                                                   u16* __restrict__ attnb) {
    __shared__ u16 kvs[2][2][2][4096];    // [group][buf][K/V][row*64 + swz col]
#if !USE_PERMLANE
    __shared__ u16 plds[8][16 * 72];
#endif
    const int t = threadIdx.x;
    const int lane = t & 63;
    const int w = (t >> 6) & 3;           // wave within group
    const int grp = t >> 8;               // 0: even jt, 1: odd jt
    const int bid = blockIdx.x;
    const int qt = 31 - (bid >> 5);       // heavy q-tiles dispatched first (LPT)
    const int p = bid & 31;
    const int nn = p >> 1, b = p & 1;
    const int i0 = qt * 64;

    const int li = lane & 15;
    const int lg = lane >> 4;

    const int qrow = i0 + w * 16 + li;
    const u16* qg = qkvb + ((size_t)qrow * 2 + b) * 3072 + nn * 64 + lg * 8;
    bf16x8 qa0 = *(const bf16x8*)(qg);
    bf16x8 qa1 = *(const bf16x8*)(qg + 32);

    f32x4 o[4] = {};                      // O[row = lg*4+r][d = cf*16+li]
    float mrun = -3.0e38f;
    float lrun = 0.f;

    const int tg = t & 255;
    const int srow = tg >> 2;             // 0..63
    const int sch = (tg & 3) * 2;         // slots {sch, sch+1}
    const u16* kg = qkvb + 1024 + nn * 64 + sch * 8;
    const u16* vg = vt + ((size_t)p * 64 + srow) * 2048 + sch * 8;
    const int swo0 = srow * 64 + ((sch ^ (srow & 7)) << 3);
    const int swo1 = srow * 64 + (((sch + 1) ^ (srow & 7)) << 3);

    const int rsk0 = (lg ^ (li & 7)) << 3;          // QK^T cols [lg*8 .. )
    const int rsk1 = ((4 + lg) ^ (li & 7)) << 3;    // QK^T cols [32+lg*8 .. )

    const int nt = qt + 1;
    const int G = (nt + 1) >> 1;          // rounds per group

    u16x8 k0, k1, v0, v1;
    if (grp < nt) {                       // stage my first tile (jt = grp)
        const u16* kgp = kg + ((size_t)(grp * 64 + srow) * 2 + b) * 3072;
        k0 = *(const u16x8*)(kgp);  k1 = *(const u16x8*)(kgp + 8);
        const u16* vgp = vg + grp * 64;
        v0 = *(const u16x8*)(vgp);  v1 = *(const u16x8*)(vgp + 8);
        *(u16x8*)&kvs[grp][0][0][swo0] = k0;  *(u16x8*)&kvs[grp][0][0][swo1] = k1;
        *(u16x8*)&kvs[grp][0][1][swo0] = v0;  *(u16x8*)&kvs[grp][0][1][swo1] = v1;
    }
    __syncthreads();

    for (int s = 0; s < G; ++s) {
        const int jt = 2 * s + grp;
        const int buf = s & 1;
        const bool active = jt < nt;      // only group 1's last round can be inactive
        if (jt + 2 < nt) {                // issue-early my next tile
            const u16* kgp = kg + ((size_t)((jt + 2) * 64 + srow) * 2 + b) * 3072;
            k0 = *(const u16x8*)(kgp);  k1 = *(const u16x8*)(kgp + 8);
            const u16* vgp = vg + (jt + 2) * 64;
            v0 = *(const u16x8*)(vgp);  v1 = *(const u16x8*)(vgp + 8);
        }

        if (active) {
            const u16* kl = &kvs[grp][buf][0][0];
            const u16* vl = &kvs[grp][buf][1][0];

            // swapped QK^T: st[cf][r] = S^T[j = jt*64+cf*16+lg*4+r][i = i0+w*16+li]
            f32x4 st[4];
            __builtin_amdgcn_s_setprio(1);
#pragma unroll
            for (int cf = 0; cf < 4; ++cf) {
                bf16x8 kb0 = *(const bf16x8*)&kl[(cf * 16 + li) * 64 + rsk0];
                bf16x8 kb1 = *(const bf16x8*)&kl[(cf * 16 + li) * 64 + rsk1];
                f32x4 z = {};
                z = __builtin_amdgcn_mfma_f32_16x16x32_bf16(kb0, qa0, z, 0, 0, 0);
                z = __builtin_amdgcn_mfma_f32_16x16x32_bf16(kb1, qa1, z, 0, 0, 0);
                st[cf] = z;
            }
            __builtin_amdgcn_s_setprio(0);

            if (jt == qt) {               // mask only the diagonal tile
                const int it = w * 16 + li;
#pragma unroll
                for (int cf = 0; cf < 4; ++cf)
#pragma unroll
                    for (int r = 0; r < 4; ++r) {
                        int jl = cf * 16 + lg * 4 + r;
                        if (jl > it) st[cf][r] = -3.0e38f;
                    }
            }

            // row max: 15 in-reg + 2 shuffles
            float mloc = st[0][0];
#pragma unroll
            for (int cf = 0; cf < 4; ++cf)
#pragma unroll
                for (int r = 0; r < 4; ++r) mloc = fmaxf(mloc, st[cf][r]);
            mloc = fmaxf(mloc, __shfl_xor(mloc, 16, 64));
            mloc = fmaxf(mloc, __shfl_xor(mloc, 32, 64));

            // defer-rescale (T13)
            if (__any(mloc > mrun + 8.0f)) {
                float mnew = fmaxf(mrun, mloc);
                float alpha = fexp2(mrun - mnew);
                lrun *= alpha;
                mrun = mnew;
#pragma unroll
                for (int r = 0; r < 4; ++r) {
                    float ar = __shfl(alpha, lg * 4 + r, 64);
#pragma unroll
                    for (int cf = 0; cf < 4; ++cf) o[cf][r] *= ar;
                }
            }

#if USE_PERMLANE
            float rsum = 0.f;
            u32 wv[4][2];
#pragma unroll
            for (int cf = 0; cf < 4; ++cf)
#pragma unroll
                for (int rr = 0; rr < 2; ++rr) {
                    float p0 = fexp2(st[cf][2 * rr] - mrun);
                    float p1 = fexp2(st[cf][2 * rr + 1] - mrun);
                    rsum += p0 + p1;
                    u32 wres;
                    asm("v_cvt_pk_bf16_f32 %0, %1, %2" : "=v"(wres) : "v"(p0), "v"(p1));
                    wv[cf][rr] = wres;
                }
            rsum += __shfl_xor(rsum, 16, 64);
            rsum += __shfl_xor(rsum, 32, 64);
            lrun += rsum;

            __builtin_amdgcn_s_setprio(1);
#pragma unroll
            for (int ks = 0; ks < 2; ++ks) {
                u32x2 sa = __builtin_amdgcn_permlane32_swap(wv[2 * ks][0], wv[2 * ks + 1][0], false, false);
                u32x2 fa = __builtin_amdgcn_permlane16_swap(sa[0], sa[1], false, false);
                u32x2 sb = __builtin_amdgcn_permlane32_swap(wv[2 * ks][1], wv[2 * ks + 1][1], false, false);
                u32x2 fb = __builtin_amdgcn_permlane16_swap(sb[0], sb[1], false, false);
                u32x4 fw = { fa[0], fb[0], fa[1], fb[1] };
                bf16x8 pa = __builtin_bit_cast(bf16x8, fw);
#pragma unroll
                for (int cf = 0; cf < 4; ++cf) {
                    bf16x8 vb = *(const bf16x8*)&vl[(cf * 16 + li) * 64
                                                    + (((ks * 4 + lg) ^ (li & 7)) << 3)];
                    o[cf] = __builtin_amdgcn_mfma_f32_16x16x32_bf16(pa, vb, o[cf], 0, 0, 0);
                }
            }
            __builtin_amdgcn_s_setprio(0);
#else
            float rsum = 0.f;
#pragma unroll
            for (int cf = 0; cf < 4; ++cf) {
                u16x4 pw;
#pragma unroll
                for (int r = 0; r < 4; ++r) {
                    float pv = fexp2(st[cf][r] - mrun);
                    rsum += pv;
                    pw[r] = f2bf(pv);
                }
                *(u16x4*)&plds[t >> 6][li * 72 + cf * 16 + lg * 4] = pw;
            }
            rsum += __shfl_xor(rsum, 16, 64);
            rsum += __shfl_xor(rsum, 32, 64);
            lrun += rsum;

            asm volatile("s_waitcnt lgkmcnt(0)" ::: "memory");
            __builtin_amdgcn_sched_barrier(0);

#pragma unroll
            for (int ks = 0; ks < 2; ++ks) {
                bf16x8 pa = *(const bf16x8*)&plds[t >> 6][li * 72 + ks * 32 + lg * 8];
#pragma unroll
                for (int cf = 0; cf < 4; ++cf) {
                    bf16x8 vb = *(const bf16x8*)&vl[(cf * 16 + li) * 64
                                                    + (((ks * 4 + lg) ^ (li & 7)) << 3)];
                    o[cf] = __builtin_amdgcn_mfma_f32_16x16x32_bf16(pa, vb, o[cf], 0, 0, 0);
                }
            }
#endif
        }

        if (jt + 2 < nt) {                // write-late my next tile into other buffer
            *(u16x8*)&kvs[grp][buf ^ 1][0][swo0] = k0;  *(u16x8*)&kvs[grp][buf ^ 1][0][swo1] = k1;
            *(u16x8*)&kvs[grp][buf ^ 1][1][swo0] = v0;  *(u16x8*)&kvs[grp][buf ^ 1][1][swo1] = v1;
        }
        __syncthreads();
    }

    // ---- merge group partials (online-softmax combine) ----
    float* osc = (float*)&kvs[1][0][0][0];       // [64 rows][65] f32 (raw scratch)
    float* msc = osc + 64 * 65;                  // [64]
    float* lsc = msc + 64;                       // [64]
    if (grp == 1) {
#pragma unroll
        for (int cf = 0; cf < 4; ++cf)
#pragma unroll
            for (int r = 0; r < 4; ++r)
                osc[(w * 16 + lg * 4 + r) * 65 + cf * 16 + li] = o[cf][r];
        if (lg == 0) { msc[w * 16 + li] = mrun; lsc[w * 16 + li] = lrun; }
    }
    __syncthreads();
    if (grp == 0) {
        float mB = msc[w * 16 + li];
        float lB = lsc[w * 16 + li];
        float m = fmaxf(mrun, mB);
        float eA = fexp2(mrun - m);
        float eB = fexp2(mB - m);
        float linv = frcp(lrun * eA + lB * eB);
#pragma unroll
        for (int r = 0; r < 4; ++r) {
            float eAr = __shfl(eA, lg * 4 + r, 64);
            float eBr = __shfl(eB, lg * 4 + r, 64);
            float rvr = __shfl(linv, lg * 4 + r, 64);
            int row = i0 + w * 16 + lg * 4 + r;
            u16* og = attnb + ((size_t)row * 2 + b) * 1024 + nn * 64;
#pragma unroll
            for (int cf = 0; cf < 4; ++cf) {
                float ob = osc[(w * 16 + lg * 4 + r) * 65 + cf * 16 + li];
                og[cf * 16 + li] = f2bf((o[cf][r] * eAr + ob * eBr) * rvr);
            }
        }
    }
}

// ---------------- residual LayerNorm (bf16 x input, f32 stats, f32 out) ----------
__global__ __launch_bounds__(256) void ln_kernel(const u16* __restrict__ Xb,
                                                 const float* __restrict__ gamma,
                                                 const float* __restrict__ beta,
                                                 float* __restrict__ out) {
    __shared__ float red[8];
    const int t = threadIdx.x;
    const int row = blockIdx.x;
    u16x4 raw = ((const u16x4*)(Xb + (size_t)row * 1024))[t];
    float vx = bf2f(raw[0]), vy = bf2f(raw[1]), vz = bf2f(raw[2]), vw = bf2f(raw[3]);
    float s = vx + vy + vz + vw;
#pragma unroll
    for (int off = 1; off < 64; off <<= 1) s += __shfl_xor(s, off, 64);
    if ((t & 63) == 0) red[t >> 6] = s;
    __syncthreads();
    float mu = (red[0] + red[1] + red[2] + red[3]) * (1.f / 1024.f);
    float dx = vx - mu, dy = vy - mu, dz = vz - mu, dw = vw - mu;
    float q = dx * dx + dy * dy + dz * dz + dw * dw;
#pragma unroll
    for (int off = 1; off < 64; off <<= 1) q += __shfl_xor(q, off, 64);
    if ((t & 63) == 0) red[4 + (t >> 6)] = q;
    __syncthreads();
    float var = (red[4] + red[5] + red[6] + red[7]) * (1.f / 1024.f);
    float rs = rsqrtf(var + 1e-5f);
    float4 g = ((const float4*)gamma)[t];
    float4 bt = ((const float4*)beta)[t];
    float4 o;
    o.x = dx * rs * g.x + bt.x;
    o.y = dy * rs * g.y + bt.y;
    o.z = dz * rs * g.z + bt.z;
    o.w = dw * rs * g.w + bt.w;
    ((float4*)(out + (size_t)row * 1024))[t] = o;
}

// ---------------- launch ----------------
extern "C" void kernel_launch(void* const* d_in, const int* in_sizes, int n_in,
                              void* d_out, int out_size, void* d_ws, size_t ws_size,
                              hipStream_t stream) {
    const float* h     = (const float*)d_in[0];
    // d_in[1] = attn_mask (deterministic causal triu; applied analytically)
    const float* Wqkv  = (const float*)d_in[2];
    const float* Wo    = (const float*)d_in[3];
    const float* gamma = (const float*)d_in[4];
    const float* beta  = (const float*)d_in[5];
    float* out = (float*)d_out;

    char* ws = (char*)d_ws;
    u16*   hb    = (u16*)(ws);
    u16*   wqkvt = (u16*)(ws + 8388608);
    u16*   wot   = (u16*)(ws + 14680064);
    u16*   qkvb  = (u16*)(ws + 16777216);
    u16*   vt    = (u16*)(ws + 41943040);
    u16*   attnb = (u16*)(ws + 50331648);
    u16*   xb    = (u16*)(ws + 58720256);    // bf16 x = h + attn_out (8.4 MB)

    const float qscale = 0.125f * 1.44269504088896f;  // 1/sqrt(Dh) * log2(e)

    prep_kernel<<<8192, 256, 0, stream>>>(h, hb, Wqkv, wqkvt, Wo, wot, qscale);
    gemm_bt_kernel<0><<<dim3(32, 24), 256, 0, stream>>>(hb, wqkvt, qkvb, vt,
                                                        nullptr, nullptr, 4096, 3072, 1024);
    attn_kernel<<<1024, 512, 0, stream>>>(qkvb, vt, attnb);
    gemm_bt_kernel<1><<<dim3(32, 8), 256, 0, stream>>>(attnb, wot, nullptr, nullptr,
                                                       hb, xb, 4096, 1024, 1024);
    ln_kernel<<<4096, 256, 0, stream>>>(xb, gamma, beta, out);
}